// Round 11
// baseline (114.116 us; speedup 1.0000x reference)
//
#include <hip/hip_runtime.h>
#include <hip/hip_bf16.h>
#include <math.h>

#define S_LEN 2048
#define NHEAD 16
#define DHEAD 128

typedef __attribute__((ext_vector_type(8)))  _Float16 f16x8;
typedef __attribute__((ext_vector_type(4)))  _Float16 f16x4;
typedef __attribute__((ext_vector_type(4)))  float    f32x4;

// async global->LDS, 16B per lane; LDS dest = wave-uniform base + lane*16
typedef __attribute__((address_space(3))) unsigned int lds_u32;
typedef __attribute__((address_space(1))) const unsigned int glb_u32;
__device__ __forceinline__ void gload16(const void* g, void* l) {
    __builtin_amdgcn_global_load_lds((glb_u32*)g, (lds_u32*)l, 16, 0, 0);
}

// ---------------------------------------------------------------------------
// Kernel 1: transpose the two SVD weight mats [H][d][e] f32 -> [H][e][d] f16
// ---------------------------------------------------------------------------
__global__ __launch_bounds__(256) void transpose_w_kernel(
    const float* __restrict__ w_qk, const float* __restrict__ w_v,
    _Float16* __restrict__ wqk_t, _Float16* __restrict__ wv_t)
{
    __shared__ float tile[32][33];
    const int mat = blockIdx.z;
    const int h   = blockIdx.y;
    const int t0  = blockIdx.x;
    const int dt  = (t0 >> 2) * 32;
    const int et  = (t0 & 3) * 32;
    const float* src = (mat ? w_v : w_qk) + (size_t)h * DHEAD * DHEAD;
    _Float16*   dst = (mat ? wv_t : wqk_t) + (size_t)h * DHEAD * DHEAD;
    const int tx = threadIdx.x & 31, ty = threadIdx.x >> 5;
#pragma unroll
    for (int k = 0; k < 4; ++k)
        tile[ty + 8 * k][tx] = src[(size_t)(dt + ty + 8 * k) * DHEAD + et + tx];
    __syncthreads();
#pragma unroll
    for (int k = 0; k < 4; ++k)
        dst[(size_t)(et + ty + 8 * k) * DHEAD + dt + tx] = (_Float16)tile[tx][ty + 8 * k];
}

// ---------------------------------------------------------------------------
// Kernel 2: per-head projection via MFMA 16x16x32 f16 (R6-verified verbatim).
//   Qp[h][s][e] = (X_q[s] @ W_qk) * log2(e)/sqrt(128)   (f16; exp2 domain)
//   Kp[h][s][e] =  X_k[s] @ W_qk                        (f16)
//   Vp[h][e][*] =  X_v[s] @ W_v, transposed AND sigma-permuted within each
//                  32-row kv block (PV B-frag in attn needs no shuffles).
// ---------------------------------------------------------------------------
__global__ __launch_bounds__(256) void proj_kernel(
    const float* __restrict__ q_in, const float* __restrict__ k_in,
    const float* __restrict__ v_in,
    const _Float16* __restrict__ wqk_t, const _Float16* __restrict__ wv_t,
    _Float16* __restrict__ Qp, _Float16* __restrict__ Kp, _Float16* __restrict__ Vp)
{
    const int h   = blockIdx.x >> 5;
    const int rb  = blockIdx.x & 31;
    const int wv  = threadIdx.x >> 6;
    const int lane = threadIdx.x & 63;
    const int r16 = lane & 15;
    const int kg  = lane >> 4;
    const int s_base = rb * 64 + wv * 16;
    const int s_row  = s_base + r16;
    // 1/sqrt(128) * log2(e)  -- softmax runs in exp2 domain
    const float INV_NORM = 0.12752211758f;

    f16x8 aq[4], ak[4], av[4];
    {
        const float* qr = q_in + ((size_t)s_row * NHEAD + h) * DHEAD;
        const float* kr = k_in + ((size_t)s_row * NHEAD + h) * DHEAD;
        const float* vr = v_in + ((size_t)s_row * NHEAD + h) * DHEAD;
#pragma unroll
        for (int kb = 0; kb < 4; ++kb) {
            const int d0 = kb * 32 + kg * 8;
            const f32x4 q0 = *(const f32x4*)(qr + d0), q1 = *(const f32x4*)(qr + d0 + 4);
            const f32x4 k0 = *(const f32x4*)(kr + d0), k1 = *(const f32x4*)(kr + d0 + 4);
            const f32x4 v0 = *(const f32x4*)(vr + d0), v1 = *(const f32x4*)(vr + d0 + 4);
#pragma unroll
            for (int i = 0; i < 4; ++i) {
                aq[kb][i] = (_Float16)q0[i];  aq[kb][i + 4] = (_Float16)q1[i];
                ak[kb][i] = (_Float16)k0[i];  ak[kb][i + 4] = (_Float16)k1[i];
                av[kb][i] = (_Float16)v0[i];  av[kb][i + 4] = (_Float16)v1[i];
            }
        }
    }

    const _Float16* wq_h = wqk_t + (size_t)h * DHEAD * DHEAD;
    const _Float16* wv_h = wv_t  + (size_t)h * DHEAD * DHEAD;

    // sigma-permuted V store offset within the 32-row block
    const int vblk_base = rb * 64 + (wv & 2) * 16;          // 32-aligned block start
    const int vslot     = kg * 8 + (wv & 1) * 4;            // chunk slot in block

#pragma unroll 2
    for (int cb = 0; cb < 8; ++cb) {
        f32x4 accq = {0.f, 0.f, 0.f, 0.f};
        f32x4 acck = {0.f, 0.f, 0.f, 0.f};
        f32x4 accv = {0.f, 0.f, 0.f, 0.f};
        const int c = cb * 16 + r16;
#pragma unroll
        for (int kb = 0; kb < 4; ++kb) {
            const f16x8 bqk = *(const f16x8*)(wq_h + (size_t)c * DHEAD + kb * 32 + kg * 8);
            const f16x8 bv  = *(const f16x8*)(wv_h + (size_t)c * DHEAD + kb * 32 + kg * 8);
            // swapped: A = weight (rows = e), B = X (cols = s)
            accq = __builtin_amdgcn_mfma_f32_16x16x32_f16(bqk, aq[kb], accq, 0, 0, 0);
            acck = __builtin_amdgcn_mfma_f32_16x16x32_f16(bqk, ak[kb], acck, 0, 0, 0);
            accv = __builtin_amdgcn_mfma_f32_16x16x32_f16(av[kb], bv,  accv, 0, 0, 0);
        }
        // Q/K: D row = e = cb*16 + kg*4 + jj, col = s = s_base + r16
        f16x4 qv, kv4;
#pragma unroll
        for (int jj = 0; jj < 4; ++jj) {
            qv[jj]  = (_Float16)(accq[jj] * INV_NORM);
            kv4[jj] = (_Float16)acck[jj];
        }
        *(f16x4*)(Qp + ((size_t)h * S_LEN + s_base + r16) * DHEAD + cb * 16 + kg * 4) = qv;
        *(f16x4*)(Kp + ((size_t)h * S_LEN + s_base + r16) * DHEAD + cb * 16 + kg * 4) = kv4;
        // V: D row = s (kg*4+jj), col = e = c  -> transposed sigma store
        f16x4 vvv;
#pragma unroll
        for (int jj = 0; jj < 4; ++jj) vvv[jj] = (_Float16)accv[jj];
        *(f16x4*)(Vp + ((size_t)h * DHEAD + c) * S_LEN + vblk_base + vslot) = vvv;
    }
}

// ---------------------------------------------------------------------------
// Kernel 3: causal flash attention — R5-verified 16q x 32kv math + R9-verified
// LDS K staging. Grid (32, H); block 512 = 8 waves:
//   tsel = w>>2, qsub = (w>>1)&1, role = w&1;
//   q-tile t = tsel ? 63-x : x (32 rows); wave owns rows [32t+16qsub, +16);
//   role r handles kv tiles j = r, r+2, ... < t+1 (2-way KV split, LDS merge).
// LOCKSTEP: all waves run I = ceil((64-x)/2) iterations; iter i covers tiles
// {2i, 2i+1}, staged once per block into LDS (8KB/tile, double-buffered =
// 32 KB) via global_load_lds with inverse-swizzled source (R9 algebra:
// addr = L ^ ((row&15)<<4); here row&15 = r16 -> conflict-free bijection).
// Softmax in-register (exp2); P in-lane via sigma (4x cvt_pkrtz, no LDS);
// V loads split in two 4-frag halves straddling the pack (caps VGPR peak).
// 4 waves/SIMD at the (512,4) cap — R5 measured 56 VGPR for this body.
// ---------------------------------------------------------------------------
__device__ __forceinline__ void stage_k2(const _Float16* kbase, _Float16* kst,
                                         int w, int lane, int par, int inext,
                                         int jmax_lock) {
#pragma unroll
    for (int cidx = 0; cidx < 2; ++cidx) {
        const int c      = 2 * w + cidx;      // 16 chunks = 2 tiles of 8KB
        const int slot   = c >> 3;            // tile slot (= role parity)
        const int cc     = c & 7;             // 1KB chunk within tile
        const int jn     = 2 * inext + slot;
        if (jn < jmax_lock) {
            const int A    = cc * 1024 + lane * 16;          // linear tile offset
            const int srcO = A ^ (((A >> 8) & 15) << 4);     // inverse swizzle
            const char* g  = (const char*)kbase + (size_t)jn * 8192 + srcO;
            char*       l  = (char*)kst + (size_t)(slot * 2 + par) * 8192
                                        + cc * 1024;         // wave-uniform base
            gload16(g, l);
        }
    }
}

__global__ __launch_bounds__(512, 4) void attn_kernel(
    const _Float16* __restrict__ Qp, const _Float16* __restrict__ Kp,
    const _Float16* __restrict__ Vp, float* __restrict__ out)
{
    __shared__ _Float16 Kst[4][4096];     // [slot*2+parity][32x128 f16] = 32 KB
    __shared__ _Float16 obuf[4][16][136];
    __shared__ float    mlbuf[4][2][16];

    const int h    = blockIdx.y;
    const int w    = threadIdx.x >> 6;
    const int lane = threadIdx.x & 63;
    const int r16  = lane & 15;
    const int kg   = lane >> 4;

    const int tsel = w >> 2;
    const int qsub = (w >> 1) & 1;
    const int role = w & 1;
    const int t    = tsel ? (63 - blockIdx.x) : blockIdx.x;
    const int mg   = tsel * 2 + qsub;
    const int q0w  = t * 32 + qsub * 16;
    const int jmax = t + 1;
    const int q_abs = q0w + r16;

    const int jmax_lock = 64 - blockIdx.x;       // heavy wave's jmax (uniform)
    const int I         = (jmax_lock + 1) >> 1;  // lockstep iterations

    const _Float16* kbase = Kp + (size_t)h * S_LEN * DHEAD;
    const _Float16* vbase = Vp + (size_t)h * DHEAD * S_LEN;

    // Q B-fragments: lane holds Q[q=r16][32*st + kg*8 + i]
    f16x8 qf[4];
    {
        const _Float16* qp = Qp + ((size_t)h * S_LEN + q_abs) * DHEAD + kg * 8;
#pragma unroll
        for (int st = 0; st < 4; ++st) qf[st] = *(const f16x8*)(qp + st * 32);
    }

    // O^T accumulators: acc[eb][jj] -> e = eb*16 + kg*4 + jj, col q = r16
    f32x4 acc[8];
#pragma unroll
    for (int eb = 0; eb < 8; ++eb) acc[eb] = (f32x4){0.f, 0.f, 0.f, 0.f};
    float m_run = -1e30f, l_run = 0.f;

    // prologue: stage tiles {0,1} into parity 0
    stage_k2(kbase, &Kst[0][0], w, lane, 0, 0, jmax_lock);

    const int sw = r16 << 4;                  // read-side swizzle
    int p = 0;
    for (int it = 0; it < I; ++it, p ^= 1) {
        __syncthreads();   // auto vmcnt(0) drain => fills for 'it' visible

        // issue async fills for iteration it+1 (opposite parity)
        if (it + 1 < I)
            stage_k2(kbase, &Kst[0][0], w, lane, p ^ 1, it + 1, jmax_lock);

        const int j = 2 * it + role;
        if (j < jmax) {
            const int kv0 = j * 32;
            const char* kt = (const char*)&Kst[role * 2 + p][0];

            // --- S^T = K.Q^T : two kv-16 halves with short K live ranges
            f32x4 s0 = {0.f, 0.f, 0.f, 0.f}, s1 = {0.f, 0.f, 0.f, 0.f};
            {
                const int Lb = r16 * 256 + kg * 16;
                const f16x8 k0 = *(const f16x8*)(kt + ((Lb      ) ^ sw));
                const f16x8 k1 = *(const f16x8*)(kt + ((Lb +  64) ^ sw));
                const f16x8 k2 = *(const f16x8*)(kt + ((Lb + 128) ^ sw));
                const f16x8 k3 = *(const f16x8*)(kt + ((Lb + 192) ^ sw));
                s0 = __builtin_amdgcn_mfma_f32_16x16x32_f16(k0, qf[0], s0, 0, 0, 0);
                s0 = __builtin_amdgcn_mfma_f32_16x16x32_f16(k1, qf[1], s0, 0, 0, 0);
                s0 = __builtin_amdgcn_mfma_f32_16x16x32_f16(k2, qf[2], s0, 0, 0, 0);
                s0 = __builtin_amdgcn_mfma_f32_16x16x32_f16(k3, qf[3], s0, 0, 0, 0);
            }
            {
                const int Lb = (16 + r16) * 256 + kg * 16;
                const f16x8 k0 = *(const f16x8*)(kt + ((Lb      ) ^ sw));
                const f16x8 k1 = *(const f16x8*)(kt + ((Lb +  64) ^ sw));
                const f16x8 k2 = *(const f16x8*)(kt + ((Lb + 128) ^ sw));
                const f16x8 k3 = *(const f16x8*)(kt + ((Lb + 192) ^ sw));
                s1 = __builtin_amdgcn_mfma_f32_16x16x32_f16(k0, qf[0], s1, 0, 0, 0);
                s1 = __builtin_amdgcn_mfma_f32_16x16x32_f16(k1, qf[1], s1, 0, 0, 0);
                s1 = __builtin_amdgcn_mfma_f32_16x16x32_f16(k2, qf[2], s1, 0, 0, 0);
                s1 = __builtin_amdgcn_mfma_f32_16x16x32_f16(k3, qf[3], s1, 0, 0, 0);
            }

            float sv[8];
#pragma unroll
            for (int i = 0; i < 4; ++i) { sv[i] = s0[i]; sv[4 + i] = s1[i]; }

            // causal mask (diagonal tile only); kv = kv0+(i>>2)*16+kg*4+(i&3)
            if (j == t) {
#pragma unroll
                for (int i = 0; i < 8; ++i) {
                    const int krel = ((i >> 2) << 4) + kg * 4 + (i & 3);
                    if (kv0 + krel > q_abs) sv[i] = -1e30f;
                }
            }

            // --- V first half issued early (hides under softmax)
            const _Float16* vp = vbase + (size_t)r16 * S_LEN + kv0 + kg * 8;
            f16x8 v0 = *(const f16x8*)(vp);
            f16x8 v1 = *(const f16x8*)(vp + 16 * S_LEN);
            f16x8 v2 = *(const f16x8*)(vp + 32 * S_LEN);
            f16x8 v3 = *(const f16x8*)(vp + 48 * S_LEN);

            // --- online softmax, per q-row = r16 (spread over 4 kg lanes)
            float t0 = fmaxf(sv[0], sv[1]), t1 = fmaxf(sv[2], sv[3]);
            float t2 = fmaxf(sv[4], sv[5]), t3 = fmaxf(sv[6], sv[7]);
            float tm = fmaxf(fmaxf(t0, t1), fmaxf(t2, t3));
            tm = fmaxf(tm, __shfl_xor(tm, 16, 64));
            tm = fmaxf(tm, __shfl_xor(tm, 32, 64));
            if (__any(tm > m_run)) {
                const float mnew = fmaxf(m_run, tm);
                const float corr = exp2f(m_run - mnew);
                l_run *= corr;
#pragma unroll
                for (int eb = 0; eb < 8; ++eb)
#pragma unroll
                    for (int jj = 0; jj < 4; ++jj) acc[eb][jj] *= corr;
                m_run = mnew;
            }
#pragma unroll
            for (int i = 0; i < 8; ++i) sv[i] = exp2f(sv[i] - m_run);
            float rs = ((sv[0] + sv[1]) + (sv[2] + sv[3]))
                     + ((sv[4] + sv[5]) + (sv[6] + sv[7]));
            rs += __shfl_xor(rs, 16, 64);
            rs += __shfl_xor(rs, 32, 64);
            l_run += rs;

            // --- PV B-fragment: entirely in-lane (sigma-permuted k-slots)
            union uf8 { unsigned w[4]; f16x8 v; } pb;
            pb.w[0] = __builtin_bit_cast(unsigned, __builtin_amdgcn_cvt_pkrtz(sv[0], sv[1]));
            pb.w[1] = __builtin_bit_cast(unsigned, __builtin_amdgcn_cvt_pkrtz(sv[2], sv[3]));
            pb.w[2] = __builtin_bit_cast(unsigned, __builtin_amdgcn_cvt_pkrtz(sv[4], sv[5]));
            pb.w[3] = __builtin_bit_cast(unsigned, __builtin_amdgcn_cvt_pkrtz(sv[6], sv[7]));

            // --- O^T += V^T . P^T, two 4-eb halves with short V live ranges
            acc[0] = __builtin_amdgcn_mfma_f32_16x16x32_f16(v0, pb.v, acc[0], 0, 0, 0);
            acc[1] = __builtin_amdgcn_mfma_f32_16x16x32_f16(v1, pb.v, acc[1], 0, 0, 0);
            acc[2] = __builtin_amdgcn_mfma_f32_16x16x32_f16(v2, pb.v, acc[2], 0, 0, 0);
            acc[3] = __builtin_amdgcn_mfma_f32_16x16x32_f16(v3, pb.v, acc[3], 0, 0, 0);
            {
                const _Float16* vp2 = vp + 64 * S_LEN;
                const f16x8 w0 = *(const f16x8*)(vp2);
                const f16x8 w1 = *(const f16x8*)(vp2 + 16 * S_LEN);
                const f16x8 w2 = *(const f16x8*)(vp2 + 32 * S_LEN);
                const f16x8 w3 = *(const f16x8*)(vp2 + 48 * S_LEN);
                acc[4] = __builtin_amdgcn_mfma_f32_16x16x32_f16(w0, pb.v, acc[4], 0, 0, 0);
                acc[5] = __builtin_amdgcn_mfma_f32_16x16x32_f16(w1, pb.v, acc[5], 0, 0, 0);
                acc[6] = __builtin_amdgcn_mfma_f32_16x16x32_f16(w2, pb.v, acc[6], 0, 0, 0);
                acc[7] = __builtin_amdgcn_mfma_f32_16x16x32_f16(w3, pb.v, acc[7], 0, 0, 0);
            }
        }
    }

    // --- KV-split combine: role1 writes partial (m,l,O) to LDS; role0 merges
    if (role) {
        if (kg == 0) { mlbuf[mg][0][r16] = m_run; mlbuf[mg][1][r16] = l_run; }
#pragma unroll
        for (int eb = 0; eb < 8; ++eb) {
            f16x4 ob;
#pragma unroll
            for (int jj = 0; jj < 4; ++jj) ob[jj] = (_Float16)acc[eb][jj];
            *(f16x4*)&obuf[mg][r16][eb * 16 + kg * 4] = ob;
        }
    }
    __syncthreads();
    if (!role) {
        const float mb = mlbuf[mg][0][r16];
        const float lb = mlbuf[mg][1][r16];
        const float ms = fmaxf(m_run, mb);
        const float ca = exp2f(m_run - ms);
        const float cb = exp2f(mb - ms);
        const float rinv = 1.0f / (l_run * ca + lb * cb);
        float* orow = out + (size_t)q_abs * (NHEAD * DHEAD) + h * DHEAD;
#pragma unroll
        for (int eb = 0; eb < 8; ++eb) {
            const f16x4 ob = *(const f16x4*)&obuf[mg][r16][eb * 16 + kg * 4];
            f32x4 vv;
#pragma unroll
            for (int jj = 0; jj < 4; ++jj)
                vv[jj] = (acc[eb][jj] * ca + (float)ob[jj] * cb) * rinv;
            *(f32x4*)(orow + eb * 16 + kg * 4) = vv;
        }
    }
}

// ---------------------------------------------------------------------------
extern "C" void kernel_launch(void* const* d_in, const int* in_sizes, int n_in,
                              void* d_out, int out_size, void* d_ws, size_t ws_size,
                              hipStream_t stream) {
    const float* q_in = (const float*)d_in[0];
    const float* k_in = (const float*)d_in[1];
    const float* v_in = (const float*)d_in[2];
    // d_in[3] = attention_mask (strict causal triu) -- implemented analytically
    const float* w_qk = (const float*)d_in[4];
    const float* w_v  = (const float*)d_in[5];
    float* out = (float*)d_out;

    const size_t mat_elems = (size_t)NHEAD * S_LEN * DHEAD;
    const size_t w_elems   = (size_t)NHEAD * DHEAD * DHEAD;
    _Float16* Qp   = (_Float16*)d_ws;
    _Float16* Kp   = Qp + mat_elems;
    _Float16* Vp   = Kp + mat_elems;
    _Float16* Wqkt = Vp + mat_elems;
    _Float16* Wvt  = Wqkt + w_elems;

    transpose_w_kernel<<<dim3(16, NHEAD, 2), dim3(256), 0, stream>>>(w_qk, w_v, Wqkt, Wvt);
    proj_kernel<<<dim3(NHEAD * 32), dim3(256), 0, stream>>>(q_in, k_in, v_in, Wqkt, Wvt, Qp, Kp, Vp);
    attn_kernel<<<dim3(32, NHEAD), dim3(512), 0, stream>>>(Qp, Kp, Vp, out);
}

// Round 12
// 89.797 us; speedup vs baseline: 1.2708x; 1.2708x over previous
//
#include <hip/hip_runtime.h>
#include <hip/hip_bf16.h>
#include <math.h>

#define S_LEN 2048
#define NHEAD 16
#define DHEAD 128

typedef __attribute__((ext_vector_type(8)))  _Float16 f16x8;
typedef __attribute__((ext_vector_type(4)))  _Float16 f16x4;
typedef __attribute__((ext_vector_type(4)))  float    f32x4;
typedef __attribute__((ext_vector_type(16))) float    f32x16;

// vdst.hi32lanes <-> vsrc.lo32lanes   (HW-verified by round-2 passing)
__device__ __forceinline__ void permswap(unsigned &a, unsigned &b) {
    asm volatile("v_permlane32_swap_b32 %0, %1" : "+v"(a), "+v"(b));
}

// async global->LDS, 16B per lane; LDS dest = wave-uniform base + lane*16
typedef __attribute__((address_space(3))) unsigned int lds_u32;
typedef __attribute__((address_space(1))) const unsigned int glb_u32;
__device__ __forceinline__ void gload16(const void* g, void* l) {
    __builtin_amdgcn_global_load_lds((glb_u32*)g, (lds_u32*)l, 16, 0, 0);
}

// ---------------------------------------------------------------------------
// Kernel 1: transpose the two SVD weight mats [H][d][e] f32 -> [H][e][d] f16
// ---------------------------------------------------------------------------
__global__ __launch_bounds__(256) void transpose_w_kernel(
    const float* __restrict__ w_qk, const float* __restrict__ w_v,
    _Float16* __restrict__ wqk_t, _Float16* __restrict__ wv_t)
{
    __shared__ float tile[32][33];
    const int mat = blockIdx.z;
    const int h   = blockIdx.y;
    const int t0  = blockIdx.x;
    const int dt  = (t0 >> 2) * 32;
    const int et  = (t0 & 3) * 32;
    const float* src = (mat ? w_v : w_qk) + (size_t)h * DHEAD * DHEAD;
    _Float16*   dst = (mat ? wv_t : wqk_t) + (size_t)h * DHEAD * DHEAD;
    const int tx = threadIdx.x & 31, ty = threadIdx.x >> 5;
#pragma unroll
    for (int k = 0; k < 4; ++k)
        tile[ty + 8 * k][tx] = src[(size_t)(dt + ty + 8 * k) * DHEAD + et + tx];
    __syncthreads();
#pragma unroll
    for (int k = 0; k < 4; ++k)
        dst[(size_t)(et + ty + 8 * k) * DHEAD + dt + tx] = (_Float16)tile[tx][ty + 8 * k];
}

// ---------------------------------------------------------------------------
// Kernel 2: per-head projection via MFMA 16x16x32 f16 (round-8-verified body).
//   Qp[h][s][e] = (X_q[s] @ W_qk) * log2(e)/sqrt(128)  (f16; exp2 domain)
//   Kp[h][s][e] =  X_k[s] @ W_qk                       (f16)
//   Vt[h][e][s] =  X_v[s] @ W_v (plain transposed)     (f16)
// ---------------------------------------------------------------------------
__global__ __launch_bounds__(256) void proj_kernel(
    const float* __restrict__ q_in, const float* __restrict__ k_in,
    const float* __restrict__ v_in,
    const _Float16* __restrict__ wqk_t, const _Float16* __restrict__ wv_t,
    _Float16* __restrict__ Qp, _Float16* __restrict__ Kp, _Float16* __restrict__ Vt)
{
    const int h   = blockIdx.x >> 5;
    const int rb  = blockIdx.x & 31;
    const int wv  = threadIdx.x >> 6;
    const int lane = threadIdx.x & 63;
    const int r16 = lane & 15;
    const int kg  = lane >> 4;
    const int s_base = rb * 64 + wv * 16;
    const int s_row  = s_base + r16;
    // 1/sqrt(128) * log2(e)  -- softmax runs in exp2 domain (R5/R10-verified)
    const float INV_NORM = 0.12752211758f;

    f16x8 aq[4], ak[4], av[4];
    {
        const float* qr = q_in + ((size_t)s_row * NHEAD + h) * DHEAD;
        const float* kr = k_in + ((size_t)s_row * NHEAD + h) * DHEAD;
        const float* vr = v_in + ((size_t)s_row * NHEAD + h) * DHEAD;
#pragma unroll
        for (int kb = 0; kb < 4; ++kb) {
            const int d0 = kb * 32 + kg * 8;
            const f32x4 q0 = *(const f32x4*)(qr + d0), q1 = *(const f32x4*)(qr + d0 + 4);
            const f32x4 k0 = *(const f32x4*)(kr + d0), k1 = *(const f32x4*)(kr + d0 + 4);
            const f32x4 v0 = *(const f32x4*)(vr + d0), v1 = *(const f32x4*)(vr + d0 + 4);
#pragma unroll
            for (int i = 0; i < 4; ++i) {
                aq[kb][i] = (_Float16)q0[i];  aq[kb][i + 4] = (_Float16)q1[i];
                ak[kb][i] = (_Float16)k0[i];  ak[kb][i + 4] = (_Float16)k1[i];
                av[kb][i] = (_Float16)v0[i];  av[kb][i + 4] = (_Float16)v1[i];
            }
        }
    }

    const _Float16* wq_h = wqk_t + (size_t)h * DHEAD * DHEAD;
    const _Float16* wv_h = wv_t  + (size_t)h * DHEAD * DHEAD;

#pragma unroll 2
    for (int cb = 0; cb < 8; ++cb) {
        f32x4 accq = {0.f, 0.f, 0.f, 0.f};
        f32x4 acck = {0.f, 0.f, 0.f, 0.f};
        f32x4 accv = {0.f, 0.f, 0.f, 0.f};
        const int c = cb * 16 + r16;
#pragma unroll
        for (int kb = 0; kb < 4; ++kb) {
            const f16x8 bqk = *(const f16x8*)(wq_h + (size_t)c * DHEAD + kb * 32 + kg * 8);
            const f16x8 bv  = *(const f16x8*)(wv_h + (size_t)c * DHEAD + kb * 32 + kg * 8);
            // swapped: A = weight (rows = e), B = X (cols = s)
            accq = __builtin_amdgcn_mfma_f32_16x16x32_f16(bqk, aq[kb], accq, 0, 0, 0);
            acck = __builtin_amdgcn_mfma_f32_16x16x32_f16(bqk, ak[kb], acck, 0, 0, 0);
            accv = __builtin_amdgcn_mfma_f32_16x16x32_f16(av[kb], bv,  accv, 0, 0, 0);
        }
        // Q/K: D row = e = cb*16 + kg*4 + jj, col = s = s_base + r16
        f16x4 qv, kv4;
#pragma unroll
        for (int jj = 0; jj < 4; ++jj) {
            qv[jj]  = (_Float16)(accq[jj] * INV_NORM);
            kv4[jj] = (_Float16)acck[jj];
        }
        *(f16x4*)(Qp + ((size_t)h * S_LEN + s_base + r16) * DHEAD + cb * 16 + kg * 4) = qv;
        *(f16x4*)(Kp + ((size_t)h * S_LEN + s_base + r16) * DHEAD + cb * 16 + kg * 4) = kv4;
        // V: D row = s = s_base + kg*4 + jj, col = e = c  (plain transpose)
        f16x4 vvv;
#pragma unroll
        for (int jj = 0; jj < 4; ++jj) vvv[jj] = (_Float16)accv[jj];
        *(f16x4*)(Vt + ((size_t)h * DHEAD + c) * S_LEN + s_base + kg * 4) = vvv;
    }
}

// ---------------------------------------------------------------------------
// Kernel 3: causal flash attention — R9-verified skeleton + micro-levers:
//   exp2-domain softmax, defer-max THR=8 (T13), s_setprio around MFMA
//   clusters (T5), V-loads hoisted to right after the barrier, l_run
//   shuffle issued after PV. Everything else byte-identical to R9.
// ---------------------------------------------------------------------------
__device__ __forceinline__ void stage_k(const _Float16* kbase, _Float16* kst,
                                        int w, int lane, int par, int inext,
                                        int jmax_lock) {
#pragma unroll
    for (int cidx = 0; cidx < 2; ++cidx) {
        const int c      = 2 * w + cidx;      // 16 chunks = 2 tiles of 8KB
        const int role_c = c >> 3;
        const int cc     = c & 7;
        const int jn     = 2 * inext + role_c;
        if (jn < jmax_lock) {
            const int A    = cc * 1024 + lane * 16;          // linear tile offset
            const int srcO = A ^ (((A >> 8) & 15) << 4);     // inverse swizzle
            const char* g  = (const char*)kbase + (size_t)jn * 8192 + srcO;
            char*       l  = (char*)kst + (size_t)(role_c * 2 + par) * 8192
                                        + cc * 1024;         // wave-uniform base
            gload16(g, l);
        }
    }
}

__global__ __launch_bounds__(512, 2) void attn_kernel(
    const _Float16* __restrict__ Qp, const _Float16* __restrict__ Kp,
    const _Float16* __restrict__ Vt, float* __restrict__ out)
{
    __shared__ _Float16 Kst[4][4096];     // [role*2+parity][32x128 f16] = 32 KB
    __shared__ _Float16 obuf[4][32][132];
    __shared__ float    mlbuf[4][2][32];

    const int h    = blockIdx.y;
    const int w    = threadIdx.x >> 6;
    const int lane = threadIdx.x & 63;
    const int q    = lane & 31;
    const int hi   = lane >> 5;

    const int qsub = w & 1;
    const int role = (w >> 1) & 1;
    const int tsel = w >> 2;
    const int t    = tsel ? (31 - blockIdx.x) : blockIdx.x;
    const int pairid = qsub + tsel * 2;
    const int q0w  = t * 64 + qsub * 32;
    const int jmax = 2 * t + 1 + qsub;
    const int q_abs = q0w + q;

    const int jmax_lock = 2 * (31 - blockIdx.x) + 2;   // block-uniform
    const int I         = jmax_lock / 2;               // lockstep iterations

    const _Float16* qbase = Qp + ((size_t)h * S_LEN + q0w) * DHEAD;
    const _Float16* kbase = Kp + (size_t)h * S_LEN * DHEAD;
    const _Float16* vbase = Vt + (size_t)h * DHEAD * S_LEN;

    const int lqk = q * DHEAD + hi * 8;   // lane offset in row-major [s][d]
    const int lv  = q * S_LEN + hi * 8;   // lane offset in [e][s]
    const int swq = (q & 15) << 4;        // read-side swizzle for K LDS

    // Q fragments (B-operand): lane holds Q[q][16m + hi*8 + i]
    f16x8 qf[8];
#pragma unroll
    for (int m = 0; m < 8; ++m)
        qf[m] = *(const f16x8*)(qbase + lqk + m * 16);

    // O^T accumulators: acc[eb] covers e = eb*32 + (i&3)+8*(i>>2)+4*hi, col q
    f32x16 acc[4];
#pragma unroll
    for (int e = 0; e < 4; ++e)
#pragma unroll
        for (int i = 0; i < 16; ++i) acc[e][i] = 0.f;

    float m_run = -1e30f, l_run = 0.f;

    // prologue: stage tiles {0,1} into parity 0
    stage_k(kbase, &Kst[0][0], w, lane, 0, 0, jmax_lock);

    int p = 0;
    for (int it = 0; it < I; ++it, p ^= 1) {
        __syncthreads();   // auto vmcnt(0) drain => fills for 'it' visible

        const int j   = 2 * it + role;
        const bool act = (j < jmax);
        const int kv0 = j * 32;

        // --- V fragments FIRST (T14-style early issue: L2 latency hides
        //     under ds_read + QK + softmax instead of softmax alone)
        f16x8 vf[8];
        if (act) {
#pragma unroll
            for (int e = 0; e < 4; ++e) {
                const _Float16* vp = vbase + (size_t)e * 32 * S_LEN + lv + kv0;
                vf[2 * e]     = *(const f16x8*)(vp);
                vf[2 * e + 1] = *(const f16x8*)(vp + 16);
            }
        }

        // --- K fragments from swizzled LDS (read BEFORE issuing next fills)
        f16x8 kf[8];
        if (act) {
            const char* kt = (const char*)&Kst[role * 2 + p][0];
#pragma unroll
            for (int m = 0; m < 8; ++m) {
                const int L = q * 256 + m * 32 + hi * 16;
                kf[m] = *(const f16x8*)(kt + (L ^ swq));
            }
        }

        // --- issue async fills for iteration it+1 (other parity buffers);
        //     issued after V loads so V's vmcnt wait excludes them.
        if (it + 1 < I)
            stage_k(kbase, &Kst[0][0], w, lane, p ^ 1, it + 1, jmax_lock);

        if (act) {
            // --- S^T = K · Q^T  (two chains to halve MFMA dep depth)
            f32x16 s0, s1;
#pragma unroll
            for (int i = 0; i < 16; ++i) { s0[i] = 0.f; s1[i] = 0.f; }
            __builtin_amdgcn_s_setprio(1);
#pragma unroll
            for (int m = 0; m < 8; m += 2) {
                s0 = __builtin_amdgcn_mfma_f32_32x32x16_f16(kf[m],     qf[m],     s0, 0, 0, 0);
                s1 = __builtin_amdgcn_mfma_f32_32x32x16_f16(kf[m + 1], qf[m + 1], s1, 0, 0, 0);
            }
            __builtin_amdgcn_s_setprio(0);

            f32x16 sv = s0 + s1;

            // --- causal mask (diagonal tile only)
            if (kv0 == q0w) {
#pragma unroll
                for (int i = 0; i < 16; ++i) {
                    const int krel = (i & 3) + 8 * (i >> 2) + 4 * hi;
                    if (kv0 + krel > q_abs) sv[i] = -1e30f;
                }
            }

            // --- in-register online softmax (per-lane = one q-row), exp2
            float t0 = fmaxf(sv[0], sv[1]),  t1 = fmaxf(sv[2], sv[3]);
            float t2 = fmaxf(sv[4], sv[5]),  t3 = fmaxf(sv[6], sv[7]);
            float t4 = fmaxf(sv[8], sv[9]),  t5 = fmaxf(sv[10], sv[11]);
            float t6 = fmaxf(sv[12], sv[13]), t7 = fmaxf(sv[14], sv[15]);
            t0 = fmaxf(t0, t1); t2 = fmaxf(t2, t3); t4 = fmaxf(t4, t5); t6 = fmaxf(t6, t7);
            float tm = fmaxf(fmaxf(t0, t2), fmaxf(t4, t6));
            tm = fmaxf(tm, __shfl_xor(tm, 32, 64));

            // defer-max (T13): rescale only when max grew by > 8 (exp2 dom:
            // P bounded by 2^8 = 256, safe in f16 pack and f32 accum)
            if (!__all(tm - m_run <= 8.0f)) {
                const float mnew = fmaxf(m_run, tm);
                const float corr = exp2f(m_run - mnew);
                l_run *= corr;
#pragma unroll
                for (int e = 0; e < 4; ++e)
#pragma unroll
                    for (int i = 0; i < 16; ++i) acc[e][i] *= corr;
                m_run = mnew;
            }

#pragma unroll
            for (int i = 0; i < 16; ++i) sv[i] = exp2f(sv[i] - m_run);
            // in-lane partial sums now; cross-half shuffle AFTER PV issue
            float r0 = (sv[0] + sv[1]) + (sv[2] + sv[3]);
            float r1 = (sv[4] + sv[5]) + (sv[6] + sv[7]);
            float r2 = (sv[8] + sv[9]) + (sv[10] + sv[11]);
            float r3 = (sv[12] + sv[13]) + (sv[14] + sv[15]);
            float rs = (r0 + r1) + (r2 + r3);

            // --- P^T pack + cross-half redistribution into PV B-fragments
            unsigned u0 = __builtin_bit_cast(unsigned, __builtin_amdgcn_cvt_pkrtz(sv[0],  sv[1]));
            unsigned u1 = __builtin_bit_cast(unsigned, __builtin_amdgcn_cvt_pkrtz(sv[2],  sv[3]));
            unsigned u2 = __builtin_bit_cast(unsigned, __builtin_amdgcn_cvt_pkrtz(sv[4],  sv[5]));
            unsigned u3 = __builtin_bit_cast(unsigned, __builtin_amdgcn_cvt_pkrtz(sv[6],  sv[7]));
            unsigned u4 = __builtin_bit_cast(unsigned, __builtin_amdgcn_cvt_pkrtz(sv[8],  sv[9]));
            unsigned u5 = __builtin_bit_cast(unsigned, __builtin_amdgcn_cvt_pkrtz(sv[10], sv[11]));
            unsigned u6 = __builtin_bit_cast(unsigned, __builtin_amdgcn_cvt_pkrtz(sv[12], sv[13]));
            unsigned u7 = __builtin_bit_cast(unsigned, __builtin_amdgcn_cvt_pkrtz(sv[14], sv[15]));
            permswap(u0, u2); permswap(u1, u3);
            permswap(u4, u6); permswap(u5, u7);
            union uf8 { unsigned w[4]; f16x8 v; };
            uf8 p0; p0.w[0] = u0; p0.w[1] = u1; p0.w[2] = u2; p0.w[3] = u3;
            uf8 p1; p1.w[0] = u4; p1.w[1] = u5; p1.w[2] = u6; p1.w[3] = u7;

            // --- O^T += V^T · P^T
            __builtin_amdgcn_s_setprio(1);
#pragma unroll
            for (int e = 0; e < 4; ++e) {
                acc[e] = __builtin_amdgcn_mfma_f32_32x32x16_f16(vf[2 * e],     p0.v, acc[e], 0, 0, 0);
                acc[e] = __builtin_amdgcn_mfma_f32_32x32x16_f16(vf[2 * e + 1], p1.v, acc[e], 0, 0, 0);
            }
            __builtin_amdgcn_s_setprio(0);

            // --- cross-half sum overlaps the MFMA pipe
            rs += __shfl_xor(rs, 32, 64);
            l_run += rs;
        }
    }

    // --- KV-split combine: role1 writes partial (m,l,O) to LDS; role0 merges
    if (role) {
        if (hi == 0) { mlbuf[pairid][0][q] = m_run; mlbuf[pairid][1][q] = l_run; }
#pragma unroll
        for (int e = 0; e < 4; ++e)
#pragma unroll
            for (int i = 0; i < 16; ++i) {
                const int erow = e * 32 + (i & 3) + 8 * (i >> 2) + 4 * hi;
                obuf[pairid][q][erow] = (_Float16)acc[e][i];
            }
    }
    __syncthreads();
    if (!role) {
        const float mb = mlbuf[pairid][0][q];
        const float lb = mlbuf[pairid][1][q];
        const float ms = fmaxf(m_run, mb);
        const float ca = exp2f(m_run - ms);
        const float cb = exp2f(mb - ms);
        const float rinv = 1.0f / (l_run * ca + lb * cb);
        float* orow = out + (size_t)q_abs * (NHEAD * DHEAD) + h * DHEAD;
#pragma unroll
        for (int e = 0; e < 4; ++e) {
#pragma unroll
            for (int g = 0; g < 4; ++g) {
                f32x4 vv;
#pragma unroll
                for (int c = 0; c < 4; ++c) {
                    const int i = g * 4 + c;
                    const int erow = e * 32 + 8 * g + 4 * hi + c;
                    vv[c] = (acc[e][i] * ca + (float)obuf[pairid][q][erow] * cb) * rinv;
                }
                *(f32x4*)(orow + e * 32 + 8 * g + 4 * hi) = vv;
            }
        }
    }
}

// ---------------------------------------------------------------------------
extern "C" void kernel_launch(void* const* d_in, const int* in_sizes, int n_in,
                              void* d_out, int out_size, void* d_ws, size_t ws_size,
                              hipStream_t stream) {
    const float* q_in = (const float*)d_in[0];
    const float* k_in = (const float*)d_in[1];
    const float* v_in = (const float*)d_in[2];
    // d_in[3] = attention_mask (strict causal triu) -- implemented analytically
    const float* w_qk = (const float*)d_in[4];
    const float* w_v  = (const float*)d_in[5];
    float* out = (float*)d_out;

    const size_t mat_elems = (size_t)NHEAD * S_LEN * DHEAD;
    const size_t w_elems   = (size_t)NHEAD * DHEAD * DHEAD;
    _Float16* Qp   = (_Float16*)d_ws;
    _Float16* Kp   = Qp + mat_elems;
    _Float16* Vt   = Kp + mat_elems;
    _Float16* Wqkt = Vt + mat_elems;
    _Float16* Wvt  = Wqkt + w_elems;

    transpose_w_kernel<<<dim3(16, NHEAD, 2), dim3(256), 0, stream>>>(w_qk, w_v, Wqkt, Wvt);
    proj_kernel<<<dim3(NHEAD * 32), dim3(256), 0, stream>>>(q_in, k_in, v_in, Wqkt, Wvt, Qp, Kp, Vt);
    attn_kernel<<<dim3(16, NHEAD), dim3(512), 0, stream>>>(Qp, Kp, Vt, out);
}

// Round 13
// 87.902 us; speedup vs baseline: 1.2982x; 1.0216x over previous
//
#include <hip/hip_runtime.h>
#include <hip/hip_bf16.h>
#include <math.h>

#define S_LEN 2048
#define NHEAD 16
#define DHEAD 128

typedef __attribute__((ext_vector_type(8)))  _Float16 f16x8;
typedef __attribute__((ext_vector_type(4)))  _Float16 f16x4;
typedef __attribute__((ext_vector_type(4)))  float    f32x4;
typedef __attribute__((ext_vector_type(16))) float    f32x16;

// vdst.hi32lanes <-> vsrc.lo32lanes   (HW-verified by round-2 passing)
__device__ __forceinline__ void permswap(unsigned &a, unsigned &b) {
    asm volatile("v_permlane32_swap_b32 %0, %1" : "+v"(a), "+v"(b));
}

// async global->LDS, 16B per lane; LDS dest = wave-uniform base + lane*16
typedef __attribute__((address_space(3))) unsigned int lds_u32;
typedef __attribute__((address_space(1))) const unsigned int glb_u32;
__device__ __forceinline__ void gload16(const void* g, void* l) {
    __builtin_amdgcn_global_load_lds((glb_u32*)g, (lds_u32*)l, 16, 0, 0);
}

// ---------------------------------------------------------------------------
// Kernel 1: transpose the two SVD weight mats [H][d][e] f32 -> [H][e][d] f16
// ---------------------------------------------------------------------------
__global__ __launch_bounds__(256) void transpose_w_kernel(
    const float* __restrict__ w_qk, const float* __restrict__ w_v,
    _Float16* __restrict__ wqk_t, _Float16* __restrict__ wv_t)
{
    __shared__ float tile[32][33];
    const int mat = blockIdx.z;
    const int h   = blockIdx.y;
    const int t0  = blockIdx.x;
    const int dt  = (t0 >> 2) * 32;
    const int et  = (t0 & 3) * 32;
    const float* src = (mat ? w_v : w_qk) + (size_t)h * DHEAD * DHEAD;
    _Float16*   dst = (mat ? wv_t : wqk_t) + (size_t)h * DHEAD * DHEAD;
    const int tx = threadIdx.x & 31, ty = threadIdx.x >> 5;
#pragma unroll
    for (int k = 0; k < 4; ++k)
        tile[ty + 8 * k][tx] = src[(size_t)(dt + ty + 8 * k) * DHEAD + et + tx];
    __syncthreads();
#pragma unroll
    for (int k = 0; k < 4; ++k)
        dst[(size_t)(et + ty + 8 * k) * DHEAD + dt + tx] = (_Float16)tile[tx][ty + 8 * k];
}

// ---------------------------------------------------------------------------
// Kernel 2: per-head projection via MFMA 16x16x32 f16 (round-8-verified body).
//   Qp[h][s][e] = (X_q[s] @ W_qk) * log2(e)/sqrt(128)  (f16; exp2 domain)
//   Kp[h][s][e] =  X_k[s] @ W_qk                       (f16)
//   Vt[h][e][s] =  X_v[s] @ W_v (plain transposed)     (f16)
// ---------------------------------------------------------------------------
__global__ __launch_bounds__(256) void proj_kernel(
    const float* __restrict__ q_in, const float* __restrict__ k_in,
    const float* __restrict__ v_in,
    const _Float16* __restrict__ wqk_t, const _Float16* __restrict__ wv_t,
    _Float16* __restrict__ Qp, _Float16* __restrict__ Kp, _Float16* __restrict__ Vt)
{
    const int h   = blockIdx.x >> 5;
    const int rb  = blockIdx.x & 31;
    const int wv  = threadIdx.x >> 6;
    const int lane = threadIdx.x & 63;
    const int r16 = lane & 15;
    const int kg  = lane >> 4;
    const int s_base = rb * 64 + wv * 16;
    const int s_row  = s_base + r16;
    // 1/sqrt(128) * log2(e)  -- softmax runs in exp2 domain (R5/R10-verified)
    const float INV_NORM = 0.12752211758f;

    f16x8 aq[4], ak[4], av[4];
    {
        const float* qr = q_in + ((size_t)s_row * NHEAD + h) * DHEAD;
        const float* kr = k_in + ((size_t)s_row * NHEAD + h) * DHEAD;
        const float* vr = v_in + ((size_t)s_row * NHEAD + h) * DHEAD;
#pragma unroll
        for (int kb = 0; kb < 4; ++kb) {
            const int d0 = kb * 32 + kg * 8;
            const f32x4 q0 = *(const f32x4*)(qr + d0), q1 = *(const f32x4*)(qr + d0 + 4);
            const f32x4 k0 = *(const f32x4*)(kr + d0), k1 = *(const f32x4*)(kr + d0 + 4);
            const f32x4 v0 = *(const f32x4*)(vr + d0), v1 = *(const f32x4*)(vr + d0 + 4);
#pragma unroll
            for (int i = 0; i < 4; ++i) {
                aq[kb][i] = (_Float16)q0[i];  aq[kb][i + 4] = (_Float16)q1[i];
                ak[kb][i] = (_Float16)k0[i];  ak[kb][i + 4] = (_Float16)k1[i];
                av[kb][i] = (_Float16)v0[i];  av[kb][i + 4] = (_Float16)v1[i];
            }
        }
    }

    const _Float16* wq_h = wqk_t + (size_t)h * DHEAD * DHEAD;
    const _Float16* wv_h = wv_t  + (size_t)h * DHEAD * DHEAD;

#pragma unroll 2
    for (int cb = 0; cb < 8; ++cb) {
        f32x4 accq = {0.f, 0.f, 0.f, 0.f};
        f32x4 acck = {0.f, 0.f, 0.f, 0.f};
        f32x4 accv = {0.f, 0.f, 0.f, 0.f};
        const int c = cb * 16 + r16;
#pragma unroll
        for (int kb = 0; kb < 4; ++kb) {
            const f16x8 bqk = *(const f16x8*)(wq_h + (size_t)c * DHEAD + kb * 32 + kg * 8);
            const f16x8 bv  = *(const f16x8*)(wv_h + (size_t)c * DHEAD + kb * 32 + kg * 8);
            // swapped: A = weight (rows = e), B = X (cols = s)
            accq = __builtin_amdgcn_mfma_f32_16x16x32_f16(bqk, aq[kb], accq, 0, 0, 0);
            acck = __builtin_amdgcn_mfma_f32_16x16x32_f16(bqk, ak[kb], acck, 0, 0, 0);
            accv = __builtin_amdgcn_mfma_f32_16x16x32_f16(av[kb], bv,  accv, 0, 0, 0);
        }
        // Q/K: D row = e = cb*16 + kg*4 + jj, col = s = s_base + r16
        f16x4 qv, kv4;
#pragma unroll
        for (int jj = 0; jj < 4; ++jj) {
            qv[jj]  = (_Float16)(accq[jj] * INV_NORM);
            kv4[jj] = (_Float16)acck[jj];
        }
        *(f16x4*)(Qp + ((size_t)h * S_LEN + s_base + r16) * DHEAD + cb * 16 + kg * 4) = qv;
        *(f16x4*)(Kp + ((size_t)h * S_LEN + s_base + r16) * DHEAD + cb * 16 + kg * 4) = kv4;
        // V: D row = s = s_base + kg*4 + jj, col = e = c  (plain transpose)
        f16x4 vvv;
#pragma unroll
        for (int jj = 0; jj < 4; ++jj) vvv[jj] = (_Float16)accv[jj];
        *(f16x4*)(Vt + ((size_t)h * DHEAD + c) * S_LEN + s_base + kg * 4) = vvv;
    }
}

// ---------------------------------------------------------------------------
// Kernel 3: causal flash attention — sequential-phase schedule:
// Grid (16, H); block 512 = 8 waves: role = w&3, qsub = w>>2.
// Phase 0: q-tile t = 31-x (heavy); phase 1: q-tile t = x (light).
// Within a phase: wave (qsub, role) owns q-rows [64t+32qsub, +32) and kv
// tiles j = 4it + role (4-way KV split, R8-verified merge). Every wave busy
// ~97% of iterations; iteration count ~17 UNIFORM across blocks.
// K staged via R10-verified stage_k4 (4 tiles/iter, double-buffered 64 KB,
// inverse-swizzled source, read XOR (q&15)<<4). Body = R12-verified:
// V-first global loads, setprio MFMA clusters, exp2 softmax, defer-max
// THR=8, in-lane P pack + permlane32_swap, late l_run shuffle.
// ---------------------------------------------------------------------------
__device__ __forceinline__ void stage_k4(const _Float16* kbase, _Float16* kst,
                                         int w, int lane, int par, int inext,
                                         int jmax_lock) {
#pragma unroll
    for (int cidx = 0; cidx < 4; ++cidx) {
        const int c    = 4 * w + cidx;        // 32 chunks = 4 tiles of 8KB
        const int slot = c >> 3;              // tile slot 0..3
        const int cc   = c & 7;               // 1KB chunk within tile
        const int jn   = 4 * inext + slot;
        if (jn < jmax_lock) {
            const int A    = cc * 1024 + lane * 16;          // linear tile offset
            const int srcO = A ^ (((A >> 8) & 15) << 4);     // inverse swizzle
            const char* g  = (const char*)kbase + (size_t)jn * 8192 + srcO;
            char*       l  = (char*)kst + (size_t)(slot * 2 + par) * 8192
                                        + cc * 1024;         // wave-uniform base
            gload16(g, l);
        }
    }
}

__global__ __launch_bounds__(512, 2) void attn_kernel(
    const _Float16* __restrict__ Qp, const _Float16* __restrict__ Kp,
    const _Float16* __restrict__ Vt, float* __restrict__ out)
{
    __shared__ _Float16 Kst[8][4096];        // [slot*2+parity] 32x128 f16 = 64 KB
    __shared__ _Float16 obuf[2][3][32][132]; // [qsub][role-1] partials ~50.7 KB
    __shared__ float    mlbuf[2][3][2][32];

    const int h    = blockIdx.y;
    const int w    = threadIdx.x >> 6;
    const int lane = threadIdx.x & 63;
    const int q    = lane & 31;
    const int hi   = lane >> 5;

    const int role = w & 3;
    const int qsub = w >> 2;

    const _Float16* kbase = Kp + (size_t)h * S_LEN * DHEAD;
    const _Float16* vbase = Vt + (size_t)h * DHEAD * S_LEN;

    const int lqk = q * DHEAD + hi * 8;   // lane offset in row-major [s][d]
    const int lv  = q * S_LEN + hi * 8;   // lane offset in [e][s]
    const int swq = (q & 15) << 4;        // read-side swizzle for K LDS

    for (int ph = 0; ph < 2; ++ph) {
        const int t     = ph ? blockIdx.x : (31 - blockIdx.x);
        const int q0w   = t * 64 + qsub * 32;
        const int jmax  = 2 * t + 1 + qsub;
        const int jlock = 2 * t + 2;            // block-uniform staging bound
        const int I     = (jlock + 3) >> 2;     // lockstep iterations
        const int q_abs = q0w + q;

        // Q fragments (B-operand): lane holds Q[q][16m + hi*8 + i]
        const _Float16* qbase = Qp + ((size_t)h * S_LEN + q0w) * DHEAD;
        f16x8 qf[8];
#pragma unroll
        for (int m = 0; m < 8; ++m)
            qf[m] = *(const f16x8*)(qbase + lqk + m * 16);

        // O^T accumulators: acc[eb] -> e = eb*32 + (i&3)+8*(i>>2)+4*hi, col q
        f32x16 acc[4];
#pragma unroll
        for (int e = 0; e < 4; ++e)
#pragma unroll
            for (int i = 0; i < 16; ++i) acc[e][i] = 0.f;
        float m_run = -1e30f, l_run = 0.f;

        // prologue: stage tiles {0..3} into parity 0
        stage_k4(kbase, &Kst[0][0], w, lane, 0, 0, jlock);

        int p = 0;
        for (int it = 0; it < I; ++it, p ^= 1) {
            __syncthreads();   // auto vmcnt(0) drain => fills for 'it' visible

            const int j   = 4 * it + role;
            const bool act = (j < jmax);
            const int kv0 = j * 32;

            // --- V fragments FIRST (L2 latency hides under ds_read+QK+softmax)
            f16x8 vf[8];
            if (act) {
#pragma unroll
                for (int e = 0; e < 4; ++e) {
                    const _Float16* vp = vbase + (size_t)e * 32 * S_LEN + lv + kv0;
                    vf[2 * e]     = *(const f16x8*)(vp);
                    vf[2 * e + 1] = *(const f16x8*)(vp + 16);
                }
            }

            // --- K fragments from swizzled LDS (before issuing next fills)
            f16x8 kf[8];
            if (act) {
                const char* kt = (const char*)&Kst[role * 2 + p][0];
#pragma unroll
                for (int m = 0; m < 8; ++m) {
                    const int L = q * 256 + m * 32 + hi * 16;
                    kf[m] = *(const f16x8*)(kt + (L ^ swq));
                }
            }

            // --- issue async fills for iteration it+1 (opposite parity)
            if (it + 1 < I)
                stage_k4(kbase, &Kst[0][0], w, lane, p ^ 1, it + 1, jlock);

            if (act) {
                // --- S^T = K · Q^T  (two chains)
                f32x16 s0, s1;
#pragma unroll
                for (int i = 0; i < 16; ++i) { s0[i] = 0.f; s1[i] = 0.f; }
                __builtin_amdgcn_s_setprio(1);
#pragma unroll
                for (int m = 0; m < 8; m += 2) {
                    s0 = __builtin_amdgcn_mfma_f32_32x32x16_f16(kf[m],     qf[m],     s0, 0, 0, 0);
                    s1 = __builtin_amdgcn_mfma_f32_32x32x16_f16(kf[m + 1], qf[m + 1], s1, 0, 0, 0);
                }
                __builtin_amdgcn_s_setprio(0);

                f32x16 sv = s0 + s1;

                // --- causal mask (diagonal tile only)
                if (kv0 == q0w) {
#pragma unroll
                    for (int i = 0; i < 16; ++i) {
                        const int krel = (i & 3) + 8 * (i >> 2) + 4 * hi;
                        if (kv0 + krel > q_abs) sv[i] = -1e30f;
                    }
                }

                // --- in-register online softmax (per-lane = one q-row), exp2
                float t0 = fmaxf(sv[0], sv[1]),  t1 = fmaxf(sv[2], sv[3]);
                float t2 = fmaxf(sv[4], sv[5]),  t3 = fmaxf(sv[6], sv[7]);
                float t4 = fmaxf(sv[8], sv[9]),  t5 = fmaxf(sv[10], sv[11]);
                float t6 = fmaxf(sv[12], sv[13]), t7 = fmaxf(sv[14], sv[15]);
                t0 = fmaxf(t0, t1); t2 = fmaxf(t2, t3);
                t4 = fmaxf(t4, t5); t6 = fmaxf(t6, t7);
                float tm = fmaxf(fmaxf(t0, t2), fmaxf(t4, t6));
                tm = fmaxf(tm, __shfl_xor(tm, 32, 64));

                // defer-max (T13): rescale only when max grew by > 8
                if (!__all(tm - m_run <= 8.0f)) {
                    const float mnew = fmaxf(m_run, tm);
                    const float corr = exp2f(m_run - mnew);
                    l_run *= corr;
#pragma unroll
                    for (int e = 0; e < 4; ++e)
#pragma unroll
                        for (int i = 0; i < 16; ++i) acc[e][i] *= corr;
                    m_run = mnew;
                }

#pragma unroll
                for (int i = 0; i < 16; ++i) sv[i] = exp2f(sv[i] - m_run);
                float r0 = (sv[0] + sv[1]) + (sv[2] + sv[3]);
                float r1 = (sv[4] + sv[5]) + (sv[6] + sv[7]);
                float r2 = (sv[8] + sv[9]) + (sv[10] + sv[11]);
                float r3 = (sv[12] + sv[13]) + (sv[14] + sv[15]);
                float rs = (r0 + r1) + (r2 + r3);

                // --- P^T pack + cross-half redistribution
                unsigned u0 = __builtin_bit_cast(unsigned, __builtin_amdgcn_cvt_pkrtz(sv[0],  sv[1]));
                unsigned u1 = __builtin_bit_cast(unsigned, __builtin_amdgcn_cvt_pkrtz(sv[2],  sv[3]));
                unsigned u2 = __builtin_bit_cast(unsigned, __builtin_amdgcn_cvt_pkrtz(sv[4],  sv[5]));
                unsigned u3 = __builtin_bit_cast(unsigned, __builtin_amdgcn_cvt_pkrtz(sv[6],  sv[7]));
                unsigned u4 = __builtin_bit_cast(unsigned, __builtin_amdgcn_cvt_pkrtz(sv[8],  sv[9]));
                unsigned u5 = __builtin_bit_cast(unsigned, __builtin_amdgcn_cvt_pkrtz(sv[10], sv[11]));
                unsigned u6 = __builtin_bit_cast(unsigned, __builtin_amdgcn_cvt_pkrtz(sv[12], sv[13]));
                unsigned u7 = __builtin_bit_cast(unsigned, __builtin_amdgcn_cvt_pkrtz(sv[14], sv[15]));
                permswap(u0, u2); permswap(u1, u3);
                permswap(u4, u6); permswap(u5, u7);
                union uf8 { unsigned w[4]; f16x8 v; };
                uf8 p0; p0.w[0] = u0; p0.w[1] = u1; p0.w[2] = u2; p0.w[3] = u3;
                uf8 p1; p1.w[0] = u4; p1.w[1] = u5; p1.w[2] = u6; p1.w[3] = u7;

                // --- O^T += V^T · P^T
                __builtin_amdgcn_s_setprio(1);
#pragma unroll
                for (int e = 0; e < 4; ++e) {
                    acc[e] = __builtin_amdgcn_mfma_f32_32x32x16_f16(vf[2 * e],     p0.v, acc[e], 0, 0, 0);
                    acc[e] = __builtin_amdgcn_mfma_f32_32x32x16_f16(vf[2 * e + 1], p1.v, acc[e], 0, 0, 0);
                }
                __builtin_amdgcn_s_setprio(0);

                // --- cross-half sum overlaps the MFMA pipe
                rs += __shfl_xor(rs, 32, 64);
                l_run += rs;
            }
        }

        // --- 4-way KV-split combine (R8-verified pattern): roles 1-3 write
        //     partial (m,l,O); role 0 merges all 4 and stores.
        if (role != 0) {
            if (hi == 0) {
                mlbuf[qsub][role - 1][0][q] = m_run;
                mlbuf[qsub][role - 1][1][q] = l_run;
            }
#pragma unroll
            for (int e = 0; e < 4; ++e)
#pragma unroll
                for (int i = 0; i < 16; ++i) {
                    const int erow = e * 32 + (i & 3) + 8 * (i >> 2) + 4 * hi;
                    obuf[qsub][role - 1][q][erow] = (_Float16)acc[e][i];
                }
        }
        __syncthreads();
        if (role == 0) {
            const float m1 = mlbuf[qsub][0][0][q], l1 = mlbuf[qsub][0][1][q];
            const float m2 = mlbuf[qsub][1][0][q], l2 = mlbuf[qsub][1][1][q];
            const float m3 = mlbuf[qsub][2][0][q], l3 = mlbuf[qsub][2][1][q];
            const float ms = fmaxf(fmaxf(m_run, m1), fmaxf(m2, m3));
            const float c0 = exp2f(m_run - ms);
            const float c1 = exp2f(m1 - ms);
            const float c2 = exp2f(m2 - ms);
            const float c3 = exp2f(m3 - ms);
            const float rinv = 1.0f / (l_run * c0 + l1 * c1 + l2 * c2 + l3 * c3);
            float* orow = out + (size_t)q_abs * (NHEAD * DHEAD) + h * DHEAD;
#pragma unroll
            for (int e = 0; e < 4; ++e) {
#pragma unroll
                for (int g = 0; g < 4; ++g) {
                    f32x4 vv;
#pragma unroll
                    for (int c = 0; c < 4; ++c) {
                        const int i = g * 4 + c;
                        const int erow = e * 32 + 8 * g + 4 * hi + c;
                        vv[c] = (acc[e][i] * c0
                                 + (float)obuf[qsub][0][q][erow] * c1
                                 + (float)obuf[qsub][1][q][erow] * c2
                                 + (float)obuf[qsub][2][q][erow] * c3) * rinv;
                    }
                    *(f32x4*)(orow + e * 32 + 8 * g + 4 * hi) = vv;
                }
            }
        }
    }
}

// ---------------------------------------------------------------------------
extern "C" void kernel_launch(void* const* d_in, const int* in_sizes, int n_in,
                              void* d_out, int out_size, void* d_ws, size_t ws_size,
                              hipStream_t stream) {
    const float* q_in = (const float*)d_in[0];
    const float* k_in = (const float*)d_in[1];
    const float* v_in = (const float*)d_in[2];
    // d_in[3] = attention_mask (strict causal triu) -- implemented analytically
    const float* w_qk = (const float*)d_in[4];
    const float* w_v  = (const float*)d_in[5];
    float* out = (float*)d_out;

    const size_t mat_elems = (size_t)NHEAD * S_LEN * DHEAD;
    const size_t w_elems   = (size_t)NHEAD * DHEAD * DHEAD;
    _Float16* Qp   = (_Float16*)d_ws;
    _Float16* Kp   = Qp + mat_elems;
    _Float16* Vt   = Kp + mat_elems;
    _Float16* Wqkt = Vt + mat_elems;
    _Float16* Wvt  = Wqkt + w_elems;

    transpose_w_kernel<<<dim3(16, NHEAD, 2), dim3(256), 0, stream>>>(w_qk, w_v, Wqkt, Wvt);
    proj_kernel<<<dim3(NHEAD * 32), dim3(256), 0, stream>>>(q_in, k_in, v_in, Wqkt, Wvt, Qp, Kp, Vt);
    attn_kernel<<<dim3(16, NHEAD), dim3(512), 0, stream>>>(Qp, Kp, Vt, out);
}